// Round 1
// baseline (1957.785 us; speedup 1.0000x reference)
//
#include <hip/hip_runtime.h>
#include <hip/hip_bf16.h>
#include <cstdint>
#include <cstddef>

typedef __bf16 bf16;
typedef __attribute__((ext_vector_type(8))) __bf16 bf16x8;
typedef __attribute__((ext_vector_type(4))) __bf16 bf16x4;
typedef __attribute__((ext_vector_type(4))) float f32x4;

// ---------------------------------------------------------------------------
// async global->LDS, 16B per lane (wave-uniform LDS base + lane*16)
__device__ __forceinline__ void gload_lds16(const void* g, void* l) {
  __builtin_amdgcn_global_load_lds(
      (const __attribute__((address_space(1))) uint32_t*)(uintptr_t)g,
      (__attribute__((address_space(3))) uint32_t*)(uintptr_t)l, 16, 0, 0);
}

// ---------------------------------------------------------------------------
// NT GEMM: C[M=4096, Npad] = act(A[M,K] * Bt[Npad,K]^T + bias)
// A, Bt bf16 row-major contiguous (lda=ldb=K). 128x128 tile, BK=32,
// 256 threads = 4 waves in 2x2, each wave 4x4 mfma_f32_16x16x32_bf16 tiles.
// ACT: 0=none, 1=tanh, 2=sigmoid. Cf (fp32) and/or Cb (bf16) outputs.
template<int ACT>
__global__ __launch_bounds__(256, 2)
void gemm_nt(const bf16* __restrict__ A, const bf16* __restrict__ Bt,
             const float* __restrict__ bias,
             float* __restrict__ Cf, bf16* __restrict__ Cb,
             int K, int Npad, int ldcf, int ldcb, int Ntrue)
{
  __shared__ __align__(16) bf16 As[128 * 32];
  __shared__ __align__(16) bf16 Bs[128 * 32];

  const int tid  = threadIdx.x;
  const int lane = tid & 63, wave = tid >> 6;
  const int wr = wave >> 1, wc = wave & 1;
  const int l15 = lane & 15, quad = lane >> 4;
  const long bm = (long)blockIdx.y * 128;
  const long bn = (long)blockIdx.x * 128;

  // staging: slot = s*256 + tid; row=slot/4, chunk-slot=slot%4,
  // global chunk = cslot ^ (row&3)  (XOR swizzle; LDS slot order == lane order)
  long aoff[2], boff[2];
  int ldsoff[2];
#pragma unroll
  for (int s = 0; s < 2; ++s) {
    int slot = s * 256 + tid;
    int row = slot >> 2, cs = slot & 3;
    int gc = cs ^ (row & 3);
    aoff[s] = (bm + row) * (long)K + gc * 8;
    boff[s] = (bn + row) * (long)K + gc * 8;
    ldsoff[s] = (s * 256 + wave * 64) * 8;   // wave-uniform base (elements)
  }

  // fragment LDS offsets: row r needs chunk q at slot q^(r&3); r&3 == lane&3
  const int cfr = (quad ^ (lane & 3)) * 8;
  int afr[4], bfr[4];
#pragma unroll
  for (int i = 0; i < 4; ++i) {
    afr[i] = (wr * 64 + i * 16 + l15) * 32 + cfr;
    bfr[i] = (wc * 64 + i * 16 + l15) * 32 + cfr;
  }

  f32x4 acc[4][4];
#pragma unroll
  for (int i = 0; i < 4; ++i)
#pragma unroll
    for (int j = 0; j < 4; ++j) acc[i][j] = {0.f, 0.f, 0.f, 0.f};

  for (int k0 = 0; k0 < K; k0 += 32) {
    __syncthreads();                       // protect LDS from previous readers
    gload_lds16(A + aoff[0] + k0, As + ldsoff[0]);
    gload_lds16(A + aoff[1] + k0, As + ldsoff[1]);
    gload_lds16(Bt + boff[0] + k0, Bs + ldsoff[0]);
    gload_lds16(Bt + boff[1] + k0, Bs + ldsoff[1]);
    __syncthreads();                       // compiler drains vmcnt before barrier

    bf16x8 av[4], bv[4];
#pragma unroll
    for (int i = 0; i < 4; ++i) av[i] = *(const bf16x8*)(As + afr[i]);
#pragma unroll
    for (int j = 0; j < 4; ++j) bv[j] = *(const bf16x8*)(Bs + bfr[j]);
#pragma unroll
    for (int i = 0; i < 4; ++i)
#pragma unroll
      for (int j = 0; j < 4; ++j)
        acc[i][j] = __builtin_amdgcn_mfma_f32_16x16x32_bf16(av[i], bv[j], acc[i][j], 0, 0, 0);
  }

  // epilogue: C/D layout col=lane&15, row=quad*4+reg
  const long row0 = bm + wr * 64 + quad * 4;
  const long col0 = bn + wc * 64 + l15;
#pragma unroll
  for (int i = 0; i < 4; ++i) {
#pragma unroll
    for (int j = 0; j < 4; ++j) {
      long c = col0 + j * 16;
      float bb = bias ? bias[c] : 0.f;
#pragma unroll
      for (int t = 0; t < 4; ++t) {
        long r = row0 + i * 16 + t;
        float v = acc[i][j][t] + bb;
        if (ACT == 1) v = tanhf(v);
        else if (ACT == 2) v = 1.f / (1.f + __expf(-v));
        if (Cf && c < Ntrue) Cf[r * ldcf + c] = v;
        if (Cb) Cb[r * ldcb + c] = (bf16)v;
      }
    }
  }
}

// ---------------------------------------------------------------------------
// dst[P x Q] = src^T zero-padded: dst[p][q] = (q<R && p<C) ? src[q][p] : 0
template<typename T>
__global__ void transpose_pad_bf16(const T* __restrict__ src, bf16* __restrict__ dst,
                                   int R, int C, int P, int Q)
{
  __shared__ float tile[32][33];
  const int q0 = blockIdx.x * 32;       // src-row block
  const int p0 = blockIdx.y * 32;       // src-col block
  const int tx = threadIdx.x & 31, ty = threadIdx.x >> 5;
#pragma unroll
  for (int y = ty; y < 32; y += 8) {
    int r = q0 + y, c = p0 + tx;
    tile[y][tx] = (r < R && c < C) ? (float)src[(long)r * C + c] : 0.f;
  }
  __syncthreads();
#pragma unroll
  for (int y = ty; y < 32; y += 8) {
    int p = p0 + y, q = q0 + tx;
    dst[(long)p * Q + q] = (bf16)tile[tx][y];
  }
}

// fp32 -> bf16, same layout, n % 4 == 0
__global__ void cvt_bf16_kernel(const float* __restrict__ s, bf16* __restrict__ d, long n)
{
  long i = ((long)blockIdx.x * blockDim.x + threadIdx.x) * 4;
  if (i >= n) return;
  float4 v = *(const float4*)(s + i);
  bf16x4 o = {(bf16)v.x, (bf16)v.y, (bf16)v.z, (bf16)v.w};
  *(bf16x4*)(d + i) = o;
}

// z = (we0*h20 + we1*h21)/(we0+we1); fp32 [4096,819] out + bf16 [4096,896]
__global__ void zkern(const float* __restrict__ h20, const float* __restrict__ h21,
                      const float* __restrict__ we, float* __restrict__ zout,
                      bf16* __restrict__ zb)
{
  const int n = blockIdx.x;
  const float w0 = we[n * 2], w1 = we[n * 2 + 1];
  const float inv = 1.f / (w0 + w1);
  for (int c = threadIdx.x; c < 896; c += 256) {
    float v = (w0 * h20[(long)n * 896 + c] + w1 * h21[(long)n * 896 + c]) * inv;
    zb[(long)n * 896 + c] = (bf16)v;
    if (c < 819) zout[(long)n * 819 + c] = v;
  }
}

// Student-t q per row + atomic column sums (one wave per row)
__global__ void qkern(const float* __restrict__ z, const float* __restrict__ cl,
                      float* __restrict__ qout, float* __restrict__ colsum)
{
  const int n = blockIdx.x;
  const int lane = threadIdx.x;
  float d0 = 0, d1 = 0, d2 = 0, d3 = 0, d4 = 0;
  for (int s = lane; s < 819; s += 64) {
    float zv = z[(long)n * 819 + s];
    float t0 = zv - cl[0 * 819 + s]; d0 += t0 * t0;
    float t1 = zv - cl[1 * 819 + s]; d1 += t1 * t1;
    float t2 = zv - cl[2 * 819 + s]; d2 += t2 * t2;
    float t3 = zv - cl[3 * 819 + s]; d3 += t3 * t3;
    float t4 = zv - cl[4 * 819 + s]; d4 += t4 * t4;
  }
#pragma unroll
  for (int off = 32; off > 0; off >>= 1) {
    d0 += __shfl_xor(d0, off);
    d1 += __shfl_xor(d1, off);
    d2 += __shfl_xor(d2, off);
    d3 += __shfl_xor(d3, off);
    d4 += __shfl_xor(d4, off);
  }
  if (lane == 0) {
    float q0 = 1.f / (1.f + d0), q1 = 1.f / (1.f + d1), q2 = 1.f / (1.f + d2);
    float q3 = 1.f / (1.f + d3), q4 = 1.f / (1.f + d4);
    float inv = 1.f / (q0 + q1 + q2 + q3 + q4);
    q0 *= inv; q1 *= inv; q2 *= inv; q3 *= inv; q4 *= inv;
    float* qr = qout + (long)n * 5;
    qr[0] = q0; qr[1] = q1; qr[2] = q2; qr[3] = q3; qr[4] = q4;
    atomicAdd(&colsum[0], q0); atomicAdd(&colsum[1], q1); atomicAdd(&colsum[2], q2);
    atomicAdd(&colsum[3], q3); atomicAdd(&colsum[4], q4);
  }
}

__global__ void pkern(const float* __restrict__ q, const float* __restrict__ colsum,
                      float* __restrict__ p)
{
  int n = blockIdx.x * blockDim.x + threadIdx.x;
  if (n >= 4096) return;
  float w[5], s = 0.f;
#pragma unroll
  for (int k = 0; k < 5; ++k) {
    float qv = q[(long)n * 5 + k];
    w[k] = qv * qv / colsum[k];
    s += w[k];
  }
  float inv = 1.f / s;
#pragma unroll
  for (int k = 0; k < 5; ++k) p[(long)n * 5 + k] = w[k] * inv;
}

struct BiasArgs {
  const float* src[8];
  float* dst[8];
  int n[8];
  int np[8];
};

__global__ void biaspad(BiasArgs a)
{
  int b = blockIdx.x;
  for (int i = threadIdx.x; i < a.np[b]; i += blockDim.x)
    a.dst[b][i] = (i < a.n[b]) ? a.src[b][i] : 0.f;
}

// ---------------------------------------------------------------------------
static inline void G(int act, const bf16* A, const bf16* Bt, const float* bias,
                     float* Cf, int ldcf, bf16* Cb, int ldcb, int K, int Npad,
                     hipStream_t stream)
{
  dim3 grid(Npad / 128, 32);
  switch (act) {
    case 0: gemm_nt<0><<<grid, 256, 0, stream>>>(A, Bt, bias, Cf, Cb, K, Npad, ldcf, ldcb, Npad); break;
    case 1: gemm_nt<1><<<grid, 256, 0, stream>>>(A, Bt, bias, Cf, Cb, K, Npad, ldcf, ldcb, Npad); break;
    case 2: gemm_nt<2><<<grid, 256, 0, stream>>>(A, Bt, bias, Cf, Cb, K, Npad, ldcf, ldcb, Npad); break;
  }
}

extern "C" void kernel_launch(void* const* d_in, const int* in_sizes, int n_in,
                              void* d_out, int out_size, void* d_ws, size_t ws_size,
                              hipStream_t stream)
{
  (void)in_sizes; (void)n_in; (void)out_size; (void)ws_size;
  const float* x0    = (const float*)d_in[0];
  const float* x1    = (const float*)d_in[1];
  const float* we    = (const float*)d_in[2];
  const float* g0    = (const float*)d_in[3];
  const float* g1    = (const float*)d_in[4];
  const float* We1_0 = (const float*)d_in[5];
  const float* be1_0 = (const float*)d_in[6];
  const float* We2_0 = (const float*)d_in[7];
  const float* be2_0 = (const float*)d_in[8];
  const float* We1_1 = (const float*)d_in[9];
  const float* be1_1 = (const float*)d_in[10];
  const float* We2_1 = (const float*)d_in[11];
  const float* be2_1 = (const float*)d_in[12];
  const float* Wd1_0 = (const float*)d_in[13];
  const float* bd1_0 = (const float*)d_in[14];
  const float* Wd2_0 = (const float*)d_in[15];
  const float* bd2_0 = (const float*)d_in[16];
  const float* Wd1_1 = (const float*)d_in[17];
  const float* bd1_1 = (const float*)d_in[18];
  const float* Wd2_1 = (const float*)d_in[19];
  const float* bd2_1 = (const float*)d_in[20];
  const float* Ww0   = (const float*)d_in[21];
  const float* Ww1   = (const float*)d_in[22];
  const float* Wf0   = (const float*)d_in[23];
  const float* Wf1   = (const float*)d_in[24];
  const float* clus  = (const float*)d_in[25];
  float* out = (float*)d_out;

  const size_t OFF_REC0 = 0;
  const size_t OFF_REC1 = 4194304;
  const size_t OFF_ADJ0 = 9437184;
  const size_t OFF_ADJ1 = 26214400;
  const size_t OFF_Z    = 42991616;
  const size_t OFF_P    = 46346240;
  const size_t OFF_Q    = 46366720;
  const size_t OFF_CL   = 46387200;

  char* ws = (char*)d_ws;
  size_t off = 0;
  auto alloc = [&](size_t bytes) -> void* {
    off = (off + 255) & ~(size_t)255;
    void* p = ws + off;
    off += bytes;
    return p;
  };
  const long N = 4096;
  bf16* g0b   = (bf16*)alloc((size_t)N * 4096 * 2);
  bf16* g1b   = (bf16*)alloc((size_t)N * 4096 * 2);
  bf16* BTe10 = (bf16*)alloc((size_t)896 * 1024 * 2);
  bf16* BTe20 = (bf16*)alloc((size_t)896 * 896 * 2);
  bf16* BTe11 = (bf16*)alloc((size_t)1024 * 1280 * 2);
  bf16* BTe21 = (bf16*)alloc((size_t)896 * 1024 * 2);
  bf16* BTd10 = (bf16*)alloc((size_t)896 * 896 * 2);
  bf16* BTd20 = (bf16*)alloc((size_t)1024 * 896 * 2);
  bf16* BTd11 = (bf16*)alloc((size_t)1024 * 896 * 2);
  bf16* BTd21 = (bf16*)alloc((size_t)1280 * 1024 * 2);
  bf16* BTw0  = (bf16*)alloc((size_t)896 * 896 * 2);
  bf16* BTw1  = (bf16*)alloc((size_t)896 * 896 * 2);
  bf16* BTf0  = (bf16*)alloc((size_t)896 * 896 * 2);
  bf16* BTf1  = (bf16*)alloc((size_t)896 * 896 * 2);
  float* pbe10 = (float*)alloc(896 * 4);
  float* pbe20 = (float*)alloc(896 * 4);
  float* pbe11 = (float*)alloc(1024 * 4);
  float* pbe21 = (float*)alloc(896 * 4);
  float* pbd10 = (float*)alloc(896 * 4);
  float* pbd20 = (float*)alloc(1024 * 4);
  float* pbd11 = (float*)alloc(1024 * 4);
  float* pbd21 = (float*)alloc(1280 * 4);
  float* h20f  = (float*)alloc((size_t)N * 896 * 4);
  float* h21f  = (float*)alloc((size_t)N * 896 * 4);
  bf16* zb     = (bf16*)alloc((size_t)N * 896 * 2);
  float* colsum = (float*)alloc(64);
  bf16* buf0 = (bf16*)alloc((size_t)N * 1280 * 2);
  bf16* buf1 = (bf16*)alloc((size_t)N * 1280 * 2);
  bf16* buf2 = (bf16*)alloc((size_t)N * 1280 * 2);
  bf16* buf3 = (bf16*)alloc((size_t)N * 1280 * 2);

  // ---- input conversions -------------------------------------------------
  cvt_bf16_kernel<<<16384, 256, 0, stream>>>(g0, g0b, N * 4096);
  cvt_bf16_kernel<<<16384, 256, 0, stream>>>(g1, g1b, N * 4096);

  auto tr = [&](const float* s, bf16* d, int R, int C, int P, int Q) {
    transpose_pad_bf16<float><<<dim3(Q / 32, P / 32), 256, 0, stream>>>(s, d, R, C, P, Q);
  };
  auto trb = [&](const bf16* s, bf16* d, int R, int C) {
    transpose_pad_bf16<bf16><<<dim3(R / 32, C / 32), 256, 0, stream>>>(s, d, R, C, C, R);
  };

  tr(We1_0, BTe10, 1024, 819, 896, 1024);
  tr(We2_0, BTe20, 819, 819, 896, 896);
  tr(We1_1, BTe11, 1280, 1024, 1024, 1280);
  tr(We2_1, BTe21, 1024, 819, 896, 1024);
  tr(Wd1_0, BTd10, 819, 819, 896, 896);
  tr(Wd2_0, BTd20, 819, 1024, 1024, 896);
  tr(Wd1_1, BTd11, 819, 1024, 1024, 896);
  tr(Wd2_1, BTd21, 1024, 1280, 1280, 1024);
  tr(Ww0, BTw0, 819, 819, 896, 896);
  tr(Ww1, BTw1, 819, 819, 896, 896);
  tr(Wf0, BTf0, 819, 819, 896, 896);
  tr(Wf1, BTf1, 819, 819, 896, 896);

  BiasArgs ba;
  {
    const float* bsrc[8] = {be1_0, be2_0, be1_1, be2_1, bd1_0, bd2_0, bd1_1, bd2_1};
    float* bdst[8] = {pbe10, pbe20, pbe11, pbe21, pbd10, pbd20, pbd11, pbd21};
    int bn_[8] = {819, 819, 1024, 819, 819, 1024, 1024, 1280};
    int bnp[8] = {896, 896, 1024, 896, 896, 1024, 1024, 1280};
    for (int i = 0; i < 8; ++i) { ba.src[i] = bsrc[i]; ba.dst[i] = bdst[i]; ba.n[i] = bn_[i]; ba.np[i] = bnp[i]; }
  }
  biaspad<<<8, 256, 0, stream>>>(ba);

  // ---- encoder 0 ---------------------------------------------------------
  tr(x0, buf3, 4096, 1024, 1024, 4096);                               // x0^T
  G(0, g0b, buf3, nullptr, nullptr, 0, buf0, 1024, 4096, 1024, stream);   // u0 = g0 x0
  G(1, buf0, BTe10, pbe10, nullptr, 0, buf1, 896, 1024, 896, stream);     // h1_0
  trb(buf1, buf2, 4096, 896);                                             // h1_0^T
  G(0, g0b, buf2, nullptr, nullptr, 0, buf0, 896, 4096, 896, stream);     // v0 = g0 h1_0
  G(1, buf0, BTe20, pbe20, h20f, 896, nullptr, 0, 896, 896, stream);      // h2_0 (fp32)

  // ---- encoder 1 ---------------------------------------------------------
  tr(x1, buf3, 4096, 1280, 1280, 4096);                               // x1^T
  G(0, g1b, buf3, nullptr, nullptr, 0, buf0, 1280, 4096, 1280, stream);   // u1
  G(1, buf0, BTe11, pbe11, nullptr, 0, buf1, 1024, 1280, 1024, stream);   // h1_1
  trb(buf1, buf2, 4096, 1024);                                            // h1_1^T
  G(0, g1b, buf2, nullptr, nullptr, 0, buf0, 1024, 4096, 1024, stream);   // v1
  G(1, buf0, BTe21, pbe21, h21f, 896, nullptr, 0, 1024, 896, stream);     // h2_1 (fp32)

  // ---- z -----------------------------------------------------------------
  zkern<<<4096, 256, 0, stream>>>(h20f, h21f, we, out + OFF_Z, zb);

  // ---- adjacency decoders ------------------------------------------------
  G(0, zb, BTw0, nullptr, nullptr, 0, buf0, 896, 896, 896, stream);       // y0 = z Ww0
  G(2, buf0, zb, nullptr, out + OFF_ADJ0, 4096, nullptr, 0, 896, 4096, stream);
  G(0, zb, BTw1, nullptr, nullptr, 0, buf0, 896, 896, 896, stream);       // y1
  G(2, buf0, zb, nullptr, out + OFF_ADJ1, 4096, nullptr, 0, 896, 4096, stream);

  // ---- feature decoder 0 -------------------------------------------------
  G(1, zb, BTf0, nullptr, nullptr, 0, buf0, 896, 896, 896, stream);       // t0 = tanh(z Wf0)
  trb(buf0, buf1, 4096, 896);                                             // t0^T
  G(0, g0b, buf1, nullptr, nullptr, 0, buf0, 896, 4096, 896, stream);     // g0 t0
  G(1, buf0, BTd10, pbd10, nullptr, 0, buf2, 896, 896, 896, stream);      // h_r0
  trb(buf2, buf1, 4096, 896);                                             // h_r0^T
  G(0, g0b, buf1, nullptr, nullptr, 0, buf0, 896, 4096, 896, stream);     // g0 h_r0
  G(1, buf0, BTd20, pbd20, out + OFF_REC0, 1024, nullptr, 0, 896, 1024, stream);

  // ---- feature decoder 1 -------------------------------------------------
  G(1, zb, BTf1, nullptr, nullptr, 0, buf0, 896, 896, 896, stream);       // t1
  trb(buf0, buf1, 4096, 896);                                             // t1^T
  G(0, g1b, buf1, nullptr, nullptr, 0, buf0, 896, 4096, 896, stream);     // g1 t1
  G(1, buf0, BTd11, pbd11, nullptr, 0, buf2, 1024, 896, 1024, stream);    // h_r1
  trb(buf2, buf1, 4096, 1024);                                            // h_r1^T
  G(0, g1b, buf1, nullptr, nullptr, 0, buf0, 1024, 4096, 1024, stream);   // g1 h_r1
  G(1, buf0, BTd21, pbd21, out + OFF_REC1, 1280, nullptr, 0, 1024, 1280, stream);

  // ---- q / p / cluster ---------------------------------------------------
  hipMemsetAsync(colsum, 0, 5 * sizeof(float), stream);
  qkern<<<4096, 64, 0, stream>>>(out + OFF_Z, clus, out + OFF_Q, colsum);
  pkern<<<16, 256, 0, stream>>>(out + OFF_Q, colsum, out + OFF_P);
  hipMemcpyAsync(out + OFF_CL, (const void*)clus, 4095 * sizeof(float),
                 hipMemcpyDeviceToDevice, stream);
}

// Round 2
// 1701.584 us; speedup vs baseline: 1.1506x; 1.1506x over previous
//
#include <hip/hip_runtime.h>
#include <hip/hip_bf16.h>
#include <cstdint>
#include <cstddef>

typedef __bf16 bf16;
typedef __attribute__((ext_vector_type(8))) __bf16 bf16x8;
typedef __attribute__((ext_vector_type(4))) __bf16 bf16x4;
typedef __attribute__((ext_vector_type(4))) float f32x4;

// ---------------------------------------------------------------------------
// async global->LDS, 16B per lane (wave-uniform LDS base + lane*16)
__device__ __forceinline__ void gload_lds16(const void* g, void* l) {
  __builtin_amdgcn_global_load_lds(
      (const __attribute__((address_space(1))) uint32_t*)(uintptr_t)g,
      (__attribute__((address_space(3))) uint32_t*)(uintptr_t)l, 16, 0, 0);
}

// ---------------------------------------------------------------------------
// NT GEMM: C[M=4096, Npad] = act(A[M,K] * Bt[Npad,K]^T + bias)
// A, Bt bf16 row-major contiguous (lda=ldb=K). 128x128 tile, BK=32,
// 256 threads = 4 waves in 2x2, each wave 4x4 mfma_f32_16x16x32_bf16 tiles.
// ACT: 0=none, 1=tanh, 2=sigmoid. Cf (fp32) and/or Cb (bf16) outputs.
template<int ACT>
__global__ __launch_bounds__(256, 2)
void gemm_nt(const bf16* __restrict__ A, const bf16* __restrict__ Bt,
             const float* __restrict__ bias,
             float* __restrict__ Cf, bf16* __restrict__ Cb,
             int K, int Npad, int ldcf, int ldcb, int Ntrue)
{
  __shared__ __align__(16) bf16 As[128 * 32];
  __shared__ __align__(16) bf16 Bs[128 * 32];

  const int tid  = threadIdx.x;
  const int lane = tid & 63, wave = tid >> 6;
  const int wr = wave >> 1, wc = wave & 1;
  const int l15 = lane & 15, quad = lane >> 4;
  const long bm = (long)blockIdx.y * 128;
  const long bn = (long)blockIdx.x * 128;

  // staging: slot = s*256 + tid; row=slot/4, chunk-slot=slot%4,
  // global chunk = cslot ^ (row&3)  (XOR swizzle; LDS slot order == lane order)
  long aoff[2], boff[2];
  int ldsoff[2];
#pragma unroll
  for (int s = 0; s < 2; ++s) {
    int slot = s * 256 + tid;
    int row = slot >> 2, cs = slot & 3;
    int gc = cs ^ (row & 3);
    aoff[s] = (bm + row) * (long)K + gc * 8;
    boff[s] = (bn + row) * (long)K + gc * 8;
    ldsoff[s] = (s * 256 + wave * 64) * 8;   // wave-uniform base (elements)
  }

  // fragment LDS offsets: row r needs chunk q at slot q^(r&3); r&3 == lane&3
  const int cfr = (quad ^ (lane & 3)) * 8;
  int afr[4], bfr[4];
#pragma unroll
  for (int i = 0; i < 4; ++i) {
    afr[i] = (wr * 64 + i * 16 + l15) * 32 + cfr;
    bfr[i] = (wc * 64 + i * 16 + l15) * 32 + cfr;
  }

  f32x4 acc[4][4];
#pragma unroll
  for (int i = 0; i < 4; ++i)
#pragma unroll
    for (int j = 0; j < 4; ++j) acc[i][j] = {0.f, 0.f, 0.f, 0.f};

  for (int k0 = 0; k0 < K; k0 += 32) {
    __syncthreads();                       // protect LDS from previous readers
    gload_lds16(A + aoff[0] + k0, As + ldsoff[0]);
    gload_lds16(A + aoff[1] + k0, As + ldsoff[1]);
    gload_lds16(Bt + boff[0] + k0, Bs + ldsoff[0]);
    gload_lds16(Bt + boff[1] + k0, Bs + ldsoff[1]);
    __syncthreads();                       // compiler drains vmcnt before barrier

    bf16x8 av[4], bv[4];
#pragma unroll
    for (int i = 0; i < 4; ++i) av[i] = *(const bf16x8*)(As + afr[i]);
#pragma unroll
    for (int j = 0; j < 4; ++j) bv[j] = *(const bf16x8*)(Bs + bfr[j]);
#pragma unroll
    for (int i = 0; i < 4; ++i)
#pragma unroll
      for (int j = 0; j < 4; ++j)
        acc[i][j] = __builtin_amdgcn_mfma_f32_16x16x32_bf16(av[i], bv[j], acc[i][j], 0, 0, 0);
  }

  // epilogue: C/D layout col=lane&15, row=quad*4+reg
  const long row0 = bm + wr * 64 + quad * 4;
  const long col0 = bn + wc * 64 + l15;
#pragma unroll
  for (int i = 0; i < 4; ++i) {
#pragma unroll
    for (int j = 0; j < 4; ++j) {
      long c = col0 + j * 16;
      float bb = bias ? bias[c] : 0.f;
#pragma unroll
      for (int t = 0; t < 4; ++t) {
        long r = row0 + i * 16 + t;
        float v = acc[i][j][t] + bb;
        if (ACT == 1) v = tanhf(v);
        else if (ACT == 2) v = 1.f / (1.f + __expf(-v));
        if (Cf && c < Ntrue) Cf[r * ldcf + c] = v;
        if (Cb) Cb[r * ldcb + c] = (bf16)v;
      }
    }
  }
}

// ---------------------------------------------------------------------------
// dst[P x Q] = src^T zero-padded: dst[p][q] = (q<R && p<C) ? src[q][p] : 0
template<typename T>
__global__ void transpose_pad_bf16(const T* __restrict__ src, bf16* __restrict__ dst,
                                   int R, int C, int P, int Q)
{
  __shared__ float tile[32][33];
  const int q0 = blockIdx.x * 32;       // src-row block
  const int p0 = blockIdx.y * 32;       // src-col block
  const int tx = threadIdx.x & 31, ty = threadIdx.x >> 5;
#pragma unroll
  for (int y = ty; y < 32; y += 8) {
    int r = q0 + y, c = p0 + tx;
    tile[y][tx] = (r < R && c < C) ? (float)src[(long)r * C + c] : 0.f;
  }
  __syncthreads();
#pragma unroll
  for (int y = ty; y < 32; y += 8) {
    int p = p0 + y, q = q0 + tx;
    dst[(long)p * Q + q] = (bf16)tile[tx][y];
  }
}

// fp32 -> bf16, same layout, n % 4 == 0
__global__ void cvt_bf16_kernel(const float* __restrict__ s, bf16* __restrict__ d, long n)
{
  long i = ((long)blockIdx.x * blockDim.x + threadIdx.x) * 4;
  if (i >= n) return;
  float4 v = *(const float4*)(s + i);
  bf16x4 o = {(bf16)v.x, (bf16)v.y, (bf16)v.z, (bf16)v.w};
  *(bf16x4*)(d + i) = o;
}

// z = (we0*h20 + we1*h21)/(we0+we1); fp32 [4096,819] out + bf16 [4096,896]
__global__ void zkern(const float* __restrict__ h20, const float* __restrict__ h21,
                      const float* __restrict__ we, float* __restrict__ zout,
                      bf16* __restrict__ zb)
{
  const int n = blockIdx.x;
  const float w0 = we[n * 2], w1 = we[n * 2 + 1];
  const float inv = 1.f / (w0 + w1);
  for (int c = threadIdx.x; c < 896; c += 256) {
    float v = (w0 * h20[(long)n * 896 + c] + w1 * h21[(long)n * 896 + c]) * inv;
    zb[(long)n * 896 + c] = (bf16)v;
    if (c < 819) zout[(long)n * 819 + c] = v;
  }
}

// Student-t q per row (one wave per row). NO atomics — colsum done separately.
__global__ void qkern(const float* __restrict__ z, const float* __restrict__ cl,
                      float* __restrict__ qout)
{
  const int n = blockIdx.x;
  const int lane = threadIdx.x;
  float d0 = 0, d1 = 0, d2 = 0, d3 = 0, d4 = 0;
  for (int s = lane; s < 819; s += 64) {
    float zv = z[(long)n * 819 + s];
    float t0 = zv - cl[0 * 819 + s]; d0 += t0 * t0;
    float t1 = zv - cl[1 * 819 + s]; d1 += t1 * t1;
    float t2 = zv - cl[2 * 819 + s]; d2 += t2 * t2;
    float t3 = zv - cl[3 * 819 + s]; d3 += t3 * t3;
    float t4 = zv - cl[4 * 819 + s]; d4 += t4 * t4;
  }
#pragma unroll
  for (int off = 32; off > 0; off >>= 1) {
    d0 += __shfl_xor(d0, off);
    d1 += __shfl_xor(d1, off);
    d2 += __shfl_xor(d2, off);
    d3 += __shfl_xor(d3, off);
    d4 += __shfl_xor(d4, off);
  }
  if (lane == 0) {
    float q0 = 1.f / (1.f + d0), q1 = 1.f / (1.f + d1), q2 = 1.f / (1.f + d2);
    float q3 = 1.f / (1.f + d3), q4 = 1.f / (1.f + d4);
    float inv = 1.f / (q0 + q1 + q2 + q3 + q4);
    float* qr = qout + (long)n * 5;
    qr[0] = q0 * inv; qr[1] = q1 * inv; qr[2] = q2 * inv;
    qr[3] = q3 * inv; qr[4] = q4 * inv;
  }
}

// colsum[k] = sum_n q[n][k]; one block per k, contention-free LDS reduction
__global__ void colsum_kern(const float* __restrict__ q, float* __restrict__ colsum)
{
  __shared__ float red[256];
  const int k = blockIdx.x;
  float s = 0.f;
  for (int n = threadIdx.x; n < 4096; n += 256) s += q[(long)n * 5 + k];
  red[threadIdx.x] = s;
  __syncthreads();
  for (int w = 128; w > 0; w >>= 1) {
    if (threadIdx.x < w) red[threadIdx.x] += red[threadIdx.x + w];
    __syncthreads();
  }
  if (threadIdx.x == 0) colsum[k] = red[0];
}

__global__ void pkern(const float* __restrict__ q, const float* __restrict__ colsum,
                      float* __restrict__ p)
{
  int n = blockIdx.x * blockDim.x + threadIdx.x;
  if (n >= 4096) return;
  float w[5], s = 0.f;
#pragma unroll
  for (int k = 0; k < 5; ++k) {
    float qv = q[(long)n * 5 + k];
    w[k] = qv * qv / colsum[k];
    s += w[k];
  }
  float inv = 1.f / s;
#pragma unroll
  for (int k = 0; k < 5; ++k) p[(long)n * 5 + k] = w[k] * inv;
}

struct BiasArgs {
  const float* src[8];
  float* dst[8];
  int n[8];
  int np[8];
};

__global__ void biaspad(BiasArgs a)
{
  int b = blockIdx.x;
  for (int i = threadIdx.x; i < a.np[b]; i += blockDim.x)
    a.dst[b][i] = (i < a.n[b]) ? a.src[b][i] : 0.f;
}

// ---------------------------------------------------------------------------
static inline void G(int act, const bf16* A, const bf16* Bt, const float* bias,
                     float* Cf, int ldcf, bf16* Cb, int ldcb, int K, int Npad,
                     hipStream_t stream)
{
  dim3 grid(Npad / 128, 32);
  switch (act) {
    case 0: gemm_nt<0><<<grid, 256, 0, stream>>>(A, Bt, bias, Cf, Cb, K, Npad, ldcf, ldcb, Npad); break;
    case 1: gemm_nt<1><<<grid, 256, 0, stream>>>(A, Bt, bias, Cf, Cb, K, Npad, ldcf, ldcb, Npad); break;
    case 2: gemm_nt<2><<<grid, 256, 0, stream>>>(A, Bt, bias, Cf, Cb, K, Npad, ldcf, ldcb, Npad); break;
  }
}

extern "C" void kernel_launch(void* const* d_in, const int* in_sizes, int n_in,
                              void* d_out, int out_size, void* d_ws, size_t ws_size,
                              hipStream_t stream)
{
  (void)in_sizes; (void)n_in; (void)out_size; (void)ws_size;
  const float* x0    = (const float*)d_in[0];
  const float* x1    = (const float*)d_in[1];
  const float* we    = (const float*)d_in[2];
  const float* g0    = (const float*)d_in[3];
  const float* g1    = (const float*)d_in[4];
  const float* We1_0 = (const float*)d_in[5];
  const float* be1_0 = (const float*)d_in[6];
  const float* We2_0 = (const float*)d_in[7];
  const float* be2_0 = (const float*)d_in[8];
  const float* We1_1 = (const float*)d_in[9];
  const float* be1_1 = (const float*)d_in[10];
  const float* We2_1 = (const float*)d_in[11];
  const float* be2_1 = (const float*)d_in[12];
  const float* Wd1_0 = (const float*)d_in[13];
  const float* bd1_0 = (const float*)d_in[14];
  const float* Wd2_0 = (const float*)d_in[15];
  const float* bd2_0 = (const float*)d_in[16];
  const float* Wd1_1 = (const float*)d_in[17];
  const float* bd1_1 = (const float*)d_in[18];
  const float* Wd2_1 = (const float*)d_in[19];
  const float* bd2_1 = (const float*)d_in[20];
  const float* Ww0   = (const float*)d_in[21];
  const float* Ww1   = (const float*)d_in[22];
  const float* Wf0   = (const float*)d_in[23];
  const float* Wf1   = (const float*)d_in[24];
  const float* clus  = (const float*)d_in[25];
  float* out = (float*)d_out;

  const size_t OFF_REC0 = 0;
  const size_t OFF_REC1 = 4194304;
  const size_t OFF_ADJ0 = 9437184;
  const size_t OFF_ADJ1 = 26214400;
  const size_t OFF_Z    = 42991616;
  const size_t OFF_P    = 46346240;
  const size_t OFF_Q    = 46366720;
  const size_t OFF_CL   = 46387200;

  char* ws = (char*)d_ws;
  size_t off = 0;
  auto alloc = [&](size_t bytes) -> void* {
    off = (off + 255) & ~(size_t)255;
    void* p = ws + off;
    off += bytes;
    return p;
  };
  const long N = 4096;
  bf16* g0b   = (bf16*)alloc((size_t)N * 4096 * 2);
  bf16* g1b   = (bf16*)alloc((size_t)N * 4096 * 2);
  bf16* BTe10 = (bf16*)alloc((size_t)896 * 1024 * 2);
  bf16* BTe20 = (bf16*)alloc((size_t)896 * 896 * 2);
  bf16* BTe11 = (bf16*)alloc((size_t)1024 * 1280 * 2);
  bf16* BTe21 = (bf16*)alloc((size_t)896 * 1024 * 2);
  bf16* BTd10 = (bf16*)alloc((size_t)896 * 896 * 2);
  bf16* BTd20 = (bf16*)alloc((size_t)1024 * 896 * 2);
  bf16* BTd11 = (bf16*)alloc((size_t)1024 * 896 * 2);
  bf16* BTd21 = (bf16*)alloc((size_t)1280 * 1024 * 2);
  bf16* BTw0  = (bf16*)alloc((size_t)896 * 896 * 2);
  bf16* BTw1  = (bf16*)alloc((size_t)896 * 896 * 2);
  bf16* BTf0  = (bf16*)alloc((size_t)896 * 896 * 2);
  bf16* BTf1  = (bf16*)alloc((size_t)896 * 896 * 2);
  float* pbe10 = (float*)alloc(896 * 4);
  float* pbe20 = (float*)alloc(896 * 4);
  float* pbe11 = (float*)alloc(1024 * 4);
  float* pbe21 = (float*)alloc(896 * 4);
  float* pbd10 = (float*)alloc(896 * 4);
  float* pbd20 = (float*)alloc(1024 * 4);
  float* pbd11 = (float*)alloc(1024 * 4);
  float* pbd21 = (float*)alloc(1280 * 4);
  float* h20f  = (float*)alloc((size_t)N * 896 * 4);
  float* h21f  = (float*)alloc((size_t)N * 896 * 4);
  bf16* zb     = (bf16*)alloc((size_t)N * 896 * 2);
  float* colsum = (float*)alloc(64);
  bf16* buf0 = (bf16*)alloc((size_t)N * 1280 * 2);
  bf16* buf1 = (bf16*)alloc((size_t)N * 1280 * 2);
  bf16* buf2 = (bf16*)alloc((size_t)N * 1280 * 2);
  bf16* buf3 = (bf16*)alloc((size_t)N * 1280 * 2);

  // ---- input conversions -------------------------------------------------
  cvt_bf16_kernel<<<16384, 256, 0, stream>>>(g0, g0b, N * 4096);
  cvt_bf16_kernel<<<16384, 256, 0, stream>>>(g1, g1b, N * 4096);

  auto tr = [&](const float* s, bf16* d, int R, int C, int P, int Q) {
    transpose_pad_bf16<float><<<dim3(Q / 32, P / 32), 256, 0, stream>>>(s, d, R, C, P, Q);
  };
  auto trb = [&](const bf16* s, bf16* d, int R, int C) {
    transpose_pad_bf16<bf16><<<dim3(R / 32, C / 32), 256, 0, stream>>>(s, d, R, C, C, R);
  };

  tr(We1_0, BTe10, 1024, 819, 896, 1024);
  tr(We2_0, BTe20, 819, 819, 896, 896);
  tr(We1_1, BTe11, 1280, 1024, 1024, 1280);
  tr(We2_1, BTe21, 1024, 819, 896, 1024);
  tr(Wd1_0, BTd10, 819, 819, 896, 896);
  tr(Wd2_0, BTd20, 819, 1024, 1024, 896);
  tr(Wd1_1, BTd11, 819, 1024, 1024, 896);
  tr(Wd2_1, BTd21, 1024, 1280, 1280, 1024);
  tr(Ww0, BTw0, 819, 819, 896, 896);
  tr(Ww1, BTw1, 819, 819, 896, 896);
  tr(Wf0, BTf0, 819, 819, 896, 896);
  tr(Wf1, BTf1, 819, 819, 896, 896);

  BiasArgs ba;
  {
    const float* bsrc[8] = {be1_0, be2_0, be1_1, be2_1, bd1_0, bd2_0, bd1_1, bd2_1};
    float* bdst[8] = {pbe10, pbe20, pbe11, pbe21, pbd10, pbd20, pbd11, pbd21};
    int bn_[8] = {819, 819, 1024, 819, 819, 1024, 1024, 1280};
    int bnp[8] = {896, 896, 1024, 896, 896, 1024, 1024, 1280};
    for (int i = 0; i < 8; ++i) { ba.src[i] = bsrc[i]; ba.dst[i] = bdst[i]; ba.n[i] = bn_[i]; ba.np[i] = bnp[i]; }
  }
  biaspad<<<8, 256, 0, stream>>>(ba);

  // ---- encoder 0 ---------------------------------------------------------
  tr(x0, buf3, 4096, 1024, 1024, 4096);                               // x0^T
  G(0, g0b, buf3, nullptr, nullptr, 0, buf0, 1024, 4096, 1024, stream);   // u0 = g0 x0
  G(1, buf0, BTe10, pbe10, nullptr, 0, buf1, 896, 1024, 896, stream);     // h1_0
  trb(buf1, buf2, 4096, 896);                                             // h1_0^T
  G(0, g0b, buf2, nullptr, nullptr, 0, buf0, 896, 4096, 896, stream);     // v0 = g0 h1_0
  G(1, buf0, BTe20, pbe20, h20f, 896, nullptr, 0, 896, 896, stream);      // h2_0 (fp32)

  // ---- encoder 1 ---------------------------------------------------------
  tr(x1, buf3, 4096, 1280, 1280, 4096);                               // x1^T
  G(0, g1b, buf3, nullptr, nullptr, 0, buf0, 1280, 4096, 1280, stream);   // u1
  G(1, buf0, BTe11, pbe11, nullptr, 0, buf1, 1024, 1280, 1024, stream);   // h1_1
  trb(buf1, buf2, 4096, 1024);                                            // h1_1^T
  G(0, g1b, buf2, nullptr, nullptr, 0, buf0, 1024, 4096, 1024, stream);   // v1
  G(1, buf0, BTe21, pbe21, h21f, 896, nullptr, 0, 1024, 896, stream);     // h2_1 (fp32)

  // ---- z -----------------------------------------------------------------
  zkern<<<4096, 256, 0, stream>>>(h20f, h21f, we, out + OFF_Z, zb);

  // ---- adjacency decoders ------------------------------------------------
  G(0, zb, BTw0, nullptr, nullptr, 0, buf0, 896, 896, 896, stream);       // y0 = z Ww0
  G(2, buf0, zb, nullptr, out + OFF_ADJ0, 4096, nullptr, 0, 896, 4096, stream);
  G(0, zb, BTw1, nullptr, nullptr, 0, buf0, 896, 896, 896, stream);       // y1
  G(2, buf0, zb, nullptr, out + OFF_ADJ1, 4096, nullptr, 0, 896, 4096, stream);

  // ---- feature decoder 0 -------------------------------------------------
  G(1, zb, BTf0, nullptr, nullptr, 0, buf0, 896, 896, 896, stream);       // t0 = tanh(z Wf0)
  trb(buf0, buf1, 4096, 896);                                             // t0^T
  G(0, g0b, buf1, nullptr, nullptr, 0, buf0, 896, 4096, 896, stream);     // g0 t0
  G(1, buf0, BTd10, pbd10, nullptr, 0, buf2, 896, 896, 896, stream);      // h_r0
  trb(buf2, buf1, 4096, 896);                                             // h_r0^T
  G(0, g0b, buf1, nullptr, nullptr, 0, buf0, 896, 4096, 896, stream);     // g0 h_r0
  G(1, buf0, BTd20, pbd20, out + OFF_REC0, 1024, nullptr, 0, 896, 1024, stream);

  // ---- feature decoder 1 -------------------------------------------------
  G(1, zb, BTf1, nullptr, nullptr, 0, buf0, 896, 896, 896, stream);       // t1
  trb(buf0, buf1, 4096, 896);                                             // t1^T
  G(0, g1b, buf1, nullptr, nullptr, 0, buf0, 896, 4096, 896, stream);     // g1 t1
  G(1, buf0, BTd11, pbd11, nullptr, 0, buf2, 1024, 896, 1024, stream);    // h_r1
  trb(buf2, buf1, 4096, 1024);                                            // h_r1^T
  G(0, g1b, buf1, nullptr, nullptr, 0, buf0, 1024, 4096, 1024, stream);   // g1 h_r1
  G(1, buf0, BTd21, pbd21, out + OFF_REC1, 1280, nullptr, 0, 1024, 1280, stream);

  // ---- q / p / cluster ---------------------------------------------------
  qkern<<<4096, 64, 0, stream>>>(out + OFF_Z, clus, out + OFF_Q);
  colsum_kern<<<5, 256, 0, stream>>>(out + OFF_Q, colsum);
  pkern<<<16, 256, 0, stream>>>(out + OFF_Q, colsum, out + OFF_P);
  hipMemcpyAsync(out + OFF_CL, (const void*)clus, 4095 * sizeof(float),
                 hipMemcpyDeviceToDevice, stream);
}